// Round 25
// baseline (167.817 us; speedup 1.0000x reference)
//
#include <hip/hip_runtime.h>
#include <stdint.h>

#define SLEN 2048
#define DMODEL 1024
#define NHEADS 16
#define MTOT 8192   // 4 * 2048

typedef short s16x8 __attribute__((ext_vector_type(8)));
typedef short s16x4 __attribute__((ext_vector_type(4)));
typedef float f32x4 __attribute__((ext_vector_type(4)));
typedef float f32x16 __attribute__((ext_vector_type(16)));
typedef unsigned u32x2 __attribute__((ext_vector_type(2)));
typedef unsigned u32x4 __attribute__((ext_vector_type(4)));

static __device__ __forceinline__ unsigned short f2bf(float f) {
  unsigned u = __builtin_bit_cast(unsigned, f);
  u += 0x7fffu + ((u >> 16) & 1u);           // RNE
  return (unsigned short)(u >> 16);
}

static __device__ __forceinline__ unsigned cvt_pk_bf16(float lo, float hi) {
  unsigned r;
  asm("v_cvt_pk_bf16_f32 %0, %1, %2" : "=v"(r) : "v"(lo), "v"(hi));
  return r;
}

static __device__ __forceinline__ void gload_lds16(const void* g, void* l) {
  __builtin_amdgcn_global_load_lds((__attribute__((address_space(1))) void*)g,
                                   (__attribute__((address_space(3))) void*)l,
                                   16, 0, 0);
}

// raw v_exp_f32 (libm exp2f adds range fixups; args <=8 finite or -3e38)
#define EXP2R(x) __builtin_amdgcn_exp2f(x)
// nested-fmax triple -> clang fuses to v_max3_f32 (T17)
#define MAX3(a, b, c) fmaxf(fmaxf((a), (b)), (c))

#define MFMA16(a, b, c) __builtin_amdgcn_mfma_f32_16x16x32_bf16(a, b, c, 0, 0, 0)
#define MFMA32(a, b, c) __builtin_amdgcn_mfma_f32_32x32x16_bf16(a, b, c, 0, 0, 0)
// full-rank row swizzle (flash): rows r, r+8, ... get distinct granule perms
#define SWZ(r) ((((r) & 7) ^ (((r) >> 3) & 7)))

// ------------- fused prep: x->bf16, W->bf16, RoPE tables (one dispatch) -----
__global__ void __launch_bounds__(256) prep(const float* __restrict__ x,
                                            const float* __restrict__ Wq,
                                            const float* __restrict__ Wk,
                                            const float* __restrict__ Wv,
                                            const float* __restrict__ Wo,
                                            const int* __restrict__ pos,
                                            unsigned short* __restrict__ xbf,
                                            unsigned short* __restrict__ wqkv,
                                            unsigned short* __restrict__ wobf,
                                            float* __restrict__ ctab,
                                            float* __restrict__ stab) {
  int blk = blockIdx.x;
  if (blk < 4096) {                           // x: 8M floats, 8/thread
    int i = blk * 256 + threadIdx.x;
    f32x4 a = ((const f32x4*)x)[i * 2];
    f32x4 b = ((const f32x4*)x)[i * 2 + 1];
    s16x8 o;
#pragma unroll
    for (int j = 0; j < 4; ++j) o[j] = (short)f2bf(a[j]);
#pragma unroll
    for (int j = 0; j < 4; ++j) o[4 + j] = (short)f2bf(b[j]);
    ((s16x8*)xbf)[i] = o;
  } else if (blk < 6144) {                    // weights: 4 x 1M floats
    int wsel = (blk - 4096) >> 9;             // 512 blocks per matrix
    const float* src = wsel == 0 ? Wq : wsel == 1 ? Wk : wsel == 2 ? Wv : Wo;
    unsigned short* dst = (wsel < 3) ? (wqkv + (size_t)wsel * DMODEL * DMODEL) : wobf;
    int i = ((blk - 4096) & 511) * 256 + threadIdx.x;
    f32x4 a = ((const f32x4*)src)[i * 2];
    f32x4 b = ((const f32x4*)src)[i * 2 + 1];
    s16x8 o;
#pragma unroll
    for (int j = 0; j < 4; ++j) o[j] = (short)f2bf(a[j]);
#pragma unroll
    for (int j = 0; j < 4; ++j) o[4 + j] = (short)f2bf(b[j]);
    ((s16x8*)dst)[i] = o;
  } else {                                    // rope tables: 65536 entries
    int g = (blk - 6144) * 256 + threadIdx.x;
    int s = g >> 5, i = g & 31;
    float p = (float)pos[s];
    float ang = p * exp2f(-(float)i * 0.41524101186092029f);
    ctab[g] = cosf(ang);
    stab[g] = sinf(ang);
  }
}

// ---------------- QKV GEMM: C[8192][3072], 256x128 tile, wave=128x64 --------
// R25: the loop is LDS-read-BW-bound (measured: 12 waves x 8 b128/k-step =
// 768cy/CU vs 230cy MFMA -> 61us, matches). Per-wave 128x64 tile cuts LDS
// reads per MFMA 33% (12 reads / 32 MFMA vs 8/16). 4 waves (2m x 2n), LDS
// 72KB 3-buf -> 2 blocks/CU. Same counted-vmcnt single-barrier loop (6
// loads/wave/stage -> vmcnt(6)). launch_bounds(256,2): 256-VGPR budget for
// acc[8][4]=128 + frags ~48 (must not spill - R10 lesson).
// Grid 768 = 3/CU sequential; XCD map: xcd owns 4 m-panels (2MB A), n in 3
// groups of 8 (2MB B).
__global__ void __launch_bounds__(256, 2) gemm_qkv(const unsigned short* __restrict__ A,
                                                   const unsigned short* __restrict__ B,
                                                   unsigned short* __restrict__ dstQ,
                                                   unsigned short* __restrict__ dstK,
                                                   unsigned short* __restrict__ dstV,
                                                   const float* __restrict__ ctab,
                                                   const float* __restrict__ stab,
                                                   float scale) {
  __shared__ unsigned short ldsA[3][256 * 32];  // 48 KB
  __shared__ unsigned short ldsB[3][128 * 32];  // 24 KB
  const int tid = threadIdx.x;
  const int lane = tid & 63;
  const int wave = tid >> 6;                  // 0..3
  const int wm = wave >> 1, wn = wave & 1;    // 2m x 2n, wave tile 128x64
  const int l15 = lane & 15, lhi = lane >> 4;

  int flat = blockIdx.y * 24 + blockIdx.x;    // 768 blocks
  int xcd = flat & 7, idx = flat >> 3;        // idx 0..95 per XCD
  int g = idx >> 5;                           // n-group 0..2
  int local = idx & 31;
  int lm = local >> 3, ln = local & 7;
  const int m0 = (xcd * 4 + lm) * 256;
  const int n0 = (g * 8 + ln) * 128;

  f32x4 acc[8][4] = {};

  // stage 256x32 A (1024 chunks, 4/thread) + 128x32 B (512 chunks, 2/thread)
  auto stage = [&](int buf, int kt) {
    const int kbase = kt * 32;
#pragma unroll
    for (int i = 0; i < 4; ++i) {
      int c = i * 256 + wave * 64 + lane;
      int row = c >> 2, kc = c & 3;
      int kcg = kc ^ ((row >> 1) & 3);
      gload_lds16(A + (size_t)(m0 + row) * 1024 + kbase + kcg * 8,
                  &ldsA[buf][(i * 256 + wave * 64) * 8]);
    }
#pragma unroll
    for (int i = 0; i < 2; ++i) {
      int c = i * 256 + wave * 64 + lane;
      int row = c >> 2, kc = c & 3;
      int kcg = kc ^ ((row >> 1) & 3);
      gload_lds16(B + (size_t)(n0 + row) * 1024 + kbase + kcg * 8,
                  &ldsB[buf][(i * 256 + wave * 64) * 8]);
    }
  };

  stage(0, 0);
  stage(1, 1);
  for (int kt = 0; kt < 32; ++kt) {
    if (kt + 1 < 32) {
      asm volatile("s_waitcnt vmcnt(6)" ::: "memory");   // stage(kt) landed
    } else {
      asm volatile("s_waitcnt vmcnt(0)" ::: "memory");
    }
    __builtin_amdgcn_s_barrier();
    __builtin_amdgcn_sched_barrier(0);
    if (kt + 2 < 32) stage((kt + 2) % 3, kt + 2);

    const int buf = kt % 3;
    s16x8 af[8], bf[4];
#pragma unroll
    for (int mi = 0; mi < 8; ++mi) {
      int row = wm * 128 + mi * 16 + l15;
      int kc = lhi ^ ((row >> 1) & 3);
      af[mi] = *(const s16x8*)&ldsA[buf][row * 32 + kc * 8];
    }
#pragma unroll
    for (int ni = 0; ni < 4; ++ni) {
      int row = wn * 64 + ni * 16 + l15;
      int kc = lhi ^ ((row >> 1) & 3);
      bf[ni] = *(const s16x8*)&ldsB[buf][row * 32 + kc * 8];
    }
    __builtin_amdgcn_s_setprio(1);
#pragma unroll
    for (int mi = 0; mi < 8; ++mi)
#pragma unroll
      for (int ni = 0; ni < 4; ++ni)
        acc[mi][ni] = MFMA16(af[mi], bf[ni], acc[mi][ni]);
    __builtin_amdgcn_s_setprio(0);
  }

  // epilogue: C layout col = lane&15, row = (lane>>4)*4 + i
  const int which = n0 >> 10;                 // 0=Q 1=K 2=V (uniform per block)
  if (which < 2) {
    unsigned short* dst = (which == 0) ? dstQ : dstK;
    const float sc = (which == 0) ? scale : 1.0f;
#pragma unroll
    for (int mi = 0; mi < 8; ++mi)
#pragma unroll
      for (int ni = 0; ni < 4; ++ni)
#pragma unroll
        for (int i = 0; i < 4; ++i) {
          int r = m0 + wm * 128 + mi * 16 + lhi * 4 + i;
          int nn = (n0 & 1023) + wn * 64 + ni * 16 + l15;
          float v = acc[mi][ni][i];
          float p = __shfl_xor(v, 1);           // RoPE partner
          int s = r & (SLEN - 1);
          int d = nn & 63;
          int fi = d >> 1;
          float c = ctab[s * 32 + fi], sn = stab[s * 32 + fi];
          float o = (d & 1) ? (p * sn + v * c) : (v * c - p * sn);
          o *= sc;
          int b = r >> 11, h = nn >> 6;
          dst[((size_t)(b * NHEADS + h) * SLEN + s) * 64 + d] = f2bf(o);
        }
  } else {  // V^T [bh][d][s], quad-permuted k-order (swap bits 2<->3 of s)
#pragma unroll
    for (int mi = 0; mi < 8; ++mi)
#pragma unroll
      for (int ni = 0; ni < 4; ++ni) {
        int r0 = m0 + wm * 128 + mi * 16 + lhi * 4;
        int nn = (n0 & 1023) + wn * 64 + ni * 16 + l15;
        int b = r0 >> 11, s0 = r0 & (SLEN - 1);
        int s0p = (s0 & ~15) | ((lhi & 1) << 3) | ((lhi & 2) << 1);
        int h = nn >> 6, d = nn & 63;
        s16x4 pk;
#pragma unroll
        for (int i = 0; i < 4; ++i) pk[i] = (short)f2bf(acc[mi][ni][i]);
        *(s16x4*)&dstV[((size_t)(b * NHEADS + h) * 64 + d) * SLEN + s0p] = pk;
      }
  }
}

// ---------------- Wo GEMM: out[8192][1024] = Obf * Wo^T (fp32 out) ----------
// Unchanged R22 structure (isolation).
__global__ void __launch_bounds__(256) gemm_wo(const unsigned short* __restrict__ A,
                                               const unsigned short* __restrict__ B,
                                               float* __restrict__ dst) {
  __shared__ unsigned short ldsA[3][128 * 32];
  __shared__ unsigned short ldsB[3][128 * 32];
  const int tid = threadIdx.x;
  const int lane = tid & 63;
  const int wave = tid >> 6;
  const int wm = wave >> 1, wn = wave & 1;

  int flat = blockIdx.y * 8 + blockIdx.x;     // 512 blocks
  int logical = (flat & 7) * 64 + (flat >> 3);
  const int m0 = (logical >> 3) * 128;
  const int n0 = (logical & 7) * 128;
  const int l15 = lane & 15, lhi = lane >> 4;

  f32x4 acc[4][4] = {};

  auto stage = [&](int buf, int kt) {
    const int kbase = kt * 32;
#pragma unroll
    for (int issue = 0; issue < 2; ++issue) {
      int c = issue * 256 + wave * 64 + lane;
      int row = c >> 2, kc = c & 3;
      int kcg = kc ^ ((row >> 1) & 3);
      gload_lds16(A + (size_t)(m0 + row) * 1024 + kbase + kcg * 8,
                  &ldsA[buf][(issue * 256 + wave * 64) * 8]);
      gload_lds16(B + (size_t)(n0 + row) * 1024 + kbase + kcg * 8,
                  &ldsB[buf][(issue * 256 + wave * 64) * 8]);
    }
  };

  stage(0, 0);
  stage(1, 1);
  for (int kt = 0; kt < 32; ++kt) {
    if (kt + 1 < 32) {
      asm volatile("s_waitcnt vmcnt(4)" ::: "memory");
    } else {
      asm volatile("s_waitcnt vmcnt(0)" ::: "memory");
    }
    __builtin_amdgcn_s_barrier();
    __builtin_amdgcn_sched_barrier(0);
    if (kt + 2 < 32) stage((kt + 2) % 3, kt + 2);

    const int buf = kt % 3;
    s16x8 af[4], bf[4];
#pragma unroll
    for (int mi = 0; mi < 4; ++mi) {
      int row = wm * 64 + mi * 16 + l15;
      int kc = lhi ^ ((row >> 1) & 3);
      af[mi] = *(const s16x8*)&ldsA[buf][row * 32 + kc * 8];
    }
#pragma unroll
    for (int ni = 0; ni < 4; ++ni) {
      int row = wn * 64 + ni * 16 + l15;
      int kc = lhi ^ ((row >> 1) & 3);
      bf[ni] = *(const s16x8*)&ldsB[buf][row * 32 + kc * 8];
    }
    __builtin_amdgcn_s_setprio(1);
#pragma unroll
    for (int mi = 0; mi < 4; ++mi)
#pragma unroll
      for (int ni = 0; ni < 4; ++ni)
        acc[mi][ni] = MFMA16(af[mi], bf[ni], acc[mi][ni]);
    __builtin_amdgcn_s_setprio(0);
  }

#pragma unroll
  for (int mi = 0; mi < 4; ++mi)
#pragma unroll
    for (int ni = 0; ni < 4; ++ni)
#pragma unroll
      for (int i = 0; i < 4; ++i) {
        int r = m0 + wm * 64 + mi * 16 + lhi * 4 + i;
        int n = n0 + wn * 64 + ni * 16 + l15;
        dst[(size_t)r * 1024 + n] = acc[mi][ni][i];
      }
}

// ---------------- causal flash attention, v19 (R24, passing) ----------------
__global__ void __launch_bounds__(256, 4) flash_attn(const unsigned short* __restrict__ Q,
                                                     const unsigned short* __restrict__ K,
                                                     const unsigned short* __restrict__ Vt,
                                                     unsigned short* __restrict__ Obf) {
  __shared__ unsigned short Kbuf[2][64 * 64];   // 8 KB each
  __shared__ unsigned short Vbuf[2][64 * 64];   // rows = d, cols = permuted k

  const int tid = threadIdx.x, lane = tid & 63, w = tid >> 6;
  const int l31 = lane & 31, h = lane >> 5;     // h: which 32-lane half

  // XCD round-robin extraction + Graeco-Latin balanced (bh, t)
  int id = blockIdx.x;                          // 0..1023
  int xcd = id & 7, idx = id >> 3;              // idx 0..127 per XCD
  const int s_ = idx & 3;
  const int bhl = (idx >> 2) & 7;
  const int g_ = idx >> 5;
  const int mul2g = (g_ == 0) ? 0 : (g_ == 1) ? 2 : (g_ == 2) ? 3 : 1;
  const int t = 4 * (s_ ^ g_) + (s_ ^ mul2g);   // 0..15, balanced both ways
  const int bh = xcd * 8 + bhl;
  const int b = bh >> 4, hd = bh & 15;

  const unsigned short* Qb = Q + (size_t)bh * SLEN * 64;
  const unsigned short* Kb = K + (size_t)bh * SLEN * 64;
  const unsigned short* Vb = Vt + (size_t)bh * 64 * SLEN;

  const int qbase = t * 128;
  const int nt = 2 * t + 2;                     // k-tiles incl. diagonal
  const int q_abs = qbase + w * 32 + l31;
  const int qminw = qbase + w * 32;

  auto stageKV = [&](int buf, int k0) {
#pragma unroll
    for (int i = 0; i < 2; ++i) {
      int c = i * 256 + tid;                    // 16B chunk 0..511
      int row = c >> 3, cg = c & 7;
      int col = ((cg ^ SWZ(row)) * 8);
      gload_lds16(Kb + (size_t)(k0 + row) * 64 + col, &Kbuf[buf][c * 8]);
      gload_lds16(Vb + (size_t)row * SLEN + k0 + col, &Vbuf[buf][c * 8]);
    }
  };

  s16x8 qf[4];
#pragma unroll
  for (int dc = 0; dc < 4; ++dc)
    qf[dc] = *(const s16x8*)&Qb[(size_t)q_abs * 64 + dc * 16 + h * 8];

  f32x16 accT[2] = {};
  float m_run = -3.0e38f, l_run = 0.f;

  stageKV(0, 0);
  for (int kt = 0; kt < nt; ++kt) {
    const int cur = kt & 1;
    const int k0 = kt * 64;
    asm volatile("s_waitcnt vmcnt(0)" ::: "memory");
    __builtin_amdgcn_s_barrier();
    __builtin_amdgcn_sched_barrier(0);
    if (kt + 1 < nt) stageKV(cur ^ 1, (kt + 1) * 64);

    if (k0 <= qminw + 31) {                     // tile contributes to this wave
      f32x16 sacc[2] = {};
      __builtin_amdgcn_s_setprio(1);
#pragma unroll
      for (int kb = 0; kb < 2; ++kb) {
#pragma unroll
        for (int dc = 0; dc < 4; ++dc) {
          int r = kb * 32 + l31;
          int g = dc * 2 + h;
          s16x8 kf = *(const s16x8*)&Kbuf[cur][r * 64 + ((g ^ SWZ(r)) * 8)];
          sacc[kb] = MFMA32(kf, qf[dc], sacc[kb]);
        }
      }
      __builtin_amdgcn_s_setprio(0);

      if (k0 + 63 > qminw) {
#pragma unroll
        for (int kb = 0; kb < 2; ++kb)
#pragma unroll
          for (int r = 0; r < 16; ++r) {
            int k_abs = k0 + kb * 32 + (r & 3) + 8 * (r >> 2) + 4 * h;
            if (k_abs > q_abs) sacc[kb][r] = -3.0e38f;
          }
      }

      // 32-value max via v_max3 trees (T17)
      float q0 = MAX3(MAX3(sacc[0][0], sacc[1][0], sacc[0][4]),
                      MAX3(sacc[1][4], sacc[0][8], sacc[1][8]),
                      fmaxf(sacc[0][12], sacc[1][12]));
      float q1 = MAX3(MAX3(sacc[0][1], sacc[1][1], sacc[0][5]),
                      MAX3(sacc[1][5], sacc[0][9], sacc[1][9]),
                      fmaxf(sacc[0][13], sacc[1][13]));
      float q2 = MAX3(MAX3(sacc[0][2], sacc[1][2], sacc[0][6]),
                      MAX3(sacc[1][6], sacc[0][10], sacc[1][10]),
                      fmaxf(sacc[0][14], sacc[1][14]));
      float q3 = MAX3(MAX3(sacc[0][3], sacc[1][3], sacc[0][7]),
                      MAX3(sacc[1][7], sacc[0][11], sacc[1][11]),
                      fmaxf(sacc[0][15], sacc[1][15]));
      float mx = MAX3(fmaxf(q0, q1), q2, q3);
      mx = fmaxf(mx, __shfl_xor(mx, 32));

      // T13 defer-max: rescale only when max grows by > 8 (exp2 domain)
      if (!__all(mx - m_run <= 8.0f)) {
        float mnew = fmaxf(m_run, mx);
        float facv = EXP2R(m_run - mnew);
        m_run = mnew;
        l_run *= facv;
#pragma unroll
        for (int db = 0; db < 2; ++db)
#pragma unroll
          for (int r = 0; r < 16; ++r) accT[db][r] *= facv;
      }

      float s0 = 0.f, s1 = 0.f, s2 = 0.f, s3 = 0.f;
#pragma unroll
      for (int kb = 0; kb < 2; ++kb)
#pragma unroll
        for (int r = 0; r < 16; r += 4) {
          float e0 = EXP2R(sacc[kb][r + 0] - m_run);
          float e1 = EXP2R(sacc[kb][r + 1] - m_run);
          float e2 = EXP2R(sacc[kb][r + 2] - m_run);
          float e3 = EXP2R(sacc[kb][r + 3] - m_run);
          sacc[kb][r + 0] = e0; sacc[kb][r + 1] = e1;
          sacc[kb][r + 2] = e2; sacc[kb][r + 3] = e3;
          s0 += e0; s1 += e1; s2 += e2; s3 += e3;
        }
      float sum = (s0 + s1) + (s2 + s3);
      sum += __shfl_xor(sum, 32);
      l_run += sum;

      unsigned Hv[8][2];
#pragma unroll
      for (int kb = 0; kb < 2; ++kb)
#pragma unroll
        for (int q4 = 0; q4 < 4; ++q4) {
          Hv[kb * 4 + q4][0] = cvt_pk_bf16(sacc[kb][q4 * 4 + 0], sacc[kb][q4 * 4 + 1]);
          Hv[kb * 4 + q4][1] = cvt_pk_bf16(sacc[kb][q4 * 4 + 2], sacc[kb][q4 * 4 + 3]);
        }

      // PV: B-frag lane-local; V-frag ONE b128 (granule 2kc+h, permuted k)
      __builtin_amdgcn_s_setprio(1);
#pragma unroll
      for (int db = 0; db < 2; ++db) {
        int r = db * 32 + l31;
        const char* rowp = (const char*)&Vbuf[cur][r * 64];
#pragma unroll
        for (int kc = 0; kc < 4; ++kc) {
          u32x4 vv = *(const u32x4*)(rowp + (((2 * kc + h) ^ SWZ(r)) * 16));
          u32x4 pv;
          pv[0] = Hv[2 * kc][0]; pv[1] = Hv[2 * kc][1];
          pv[2] = Hv[2 * kc + 1][0]; pv[3] = Hv[2 * kc + 1][1];
          accT[db] = MFMA32(__builtin_bit_cast(s16x8, vv),
                            __builtin_bit_cast(s16x8, pv), accT[db]);
        }
      }
      __builtin_amdgcn_s_setprio(0);
    }
  }

  float linv = 1.f / l_run;
#pragma unroll
  for (int db = 0; db < 2; ++db)
#pragma unroll
    for (int q4 = 0; q4 < 4; ++q4) {
      u32x2 pk;
      pk[0] = cvt_pk_bf16(accT[db][q4 * 4 + 0] * linv, accT[db][q4 * 4 + 1] * linv);
      pk[1] = cvt_pk_bf16(accT[db][q4 * 4 + 2] * linv, accT[db][q4 * 4 + 3] * linv);
      int d0 = db * 32 + 8 * q4 + 4 * h;
      *(u32x2*)&Obf[((size_t)(b * SLEN + q_abs)) * DMODEL + hd * 64 + d0] = pk;
    }
}

extern "C" void kernel_launch(void* const* d_in, const int* in_sizes, int n_in,
                              void* d_out, int out_size, void* d_ws, size_t ws_size,
                              hipStream_t stream) {
  const float* x  = (const float*)d_in[0];
  const float* Wq = (const float*)d_in[1];
  const float* Wk = (const float*)d_in[2];
  const float* Wv = (const float*)d_in[3];
  const float* Wo = (const float*)d_in[4];
  const int* pos  = (const int*)d_in[5];
  float* out = (float*)d_out;

  char* ws = (char*)d_ws;
  size_t off = 0;
  auto take = [&](size_t bytes) {
    char* p = ws + off;
    off += (bytes + 255) & ~(size_t)255;
    return p;
  };
  unsigned short* xbf  = (unsigned short*)take((size_t)MTOT * DMODEL * 2);
  unsigned short* wqkv = (unsigned short*)take((size_t)3 * DMODEL * DMODEL * 2);
  unsigned short* wobf = (unsigned short*)take((size_t)DMODEL * DMODEL * 2);
  unsigned short* Qs   = (unsigned short*)take((size_t)64 * SLEN * 64 * 2);
  unsigned short* Ks   = (unsigned short*)take((size_t)64 * SLEN * 64 * 2);
  unsigned short* Vt   = (unsigned short*)take((size_t)64 * 64 * SLEN * 2);
  unsigned short* Obf  = (unsigned short*)take((size_t)MTOT * DMODEL * 2);
  float* ctab = (float*)take((size_t)SLEN * 32 * 4);
  float* stab = (float*)take((size_t)SLEN * 32 * 4);

  // one fused prep dispatch: x-cvt (4096 blk) + W-cvt (2048) + rope (256)
  prep<<<6400, 256, 0, stream>>>(x, Wq, Wk, Wv, Wo, pos,
                                 xbf, wqkv, wobf, ctab, stab);

  // fused QKV projection: 256x128 tiles, per-wave 128x64, 768 blocks (3/CU)
  gemm_qkv<<<dim3(24, 32), 256, 0, stream>>>(xbf, wqkv, Qs, Ks, Vt,
                                             ctab, stab, 0.18033688011112042f);

  flash_attn<<<1024, 256, 0, stream>>>(Qs, Ks, Vt, Obf);

  // final projection, fp32 output
  gemm_wo<<<dim3(8, 64), 256, 0, stream>>>(Obf, wobf, out);
}

// Round 26
// 161.467 us; speedup vs baseline: 1.0393x; 1.0393x over previous
//
#include <hip/hip_runtime.h>
#include <stdint.h>

#define SLEN 2048
#define DMODEL 1024
#define NHEADS 16
#define MTOT 8192   // 4 * 2048

typedef short s16x8 __attribute__((ext_vector_type(8)));
typedef short s16x4 __attribute__((ext_vector_type(4)));
typedef float f32x4 __attribute__((ext_vector_type(4)));
typedef float f32x16 __attribute__((ext_vector_type(16)));
typedef unsigned u32x2 __attribute__((ext_vector_type(2)));
typedef unsigned u32x4 __attribute__((ext_vector_type(4)));

static __device__ __forceinline__ unsigned short f2bf(float f) {
  unsigned u = __builtin_bit_cast(unsigned, f);
  u += 0x7fffu + ((u >> 16) & 1u);           // RNE
  return (unsigned short)(u >> 16);
}

static __device__ __forceinline__ unsigned cvt_pk_bf16(float lo, float hi) {
  unsigned r;
  asm("v_cvt_pk_bf16_f32 %0, %1, %2" : "=v"(r) : "v"(lo), "v"(hi));
  return r;
}

static __device__ __forceinline__ void gload_lds16(const void* g, void* l) {
  __builtin_amdgcn_global_load_lds((__attribute__((address_space(1))) void*)g,
                                   (__attribute__((address_space(3))) void*)l,
                                   16, 0, 0);
}

// raw v_exp_f32 (libm exp2f adds range fixups; args <=8 finite or -3e38)
#define EXP2R(x) __builtin_amdgcn_exp2f(x)
// nested-fmax triple -> clang fuses to v_max3_f32 (T17)
#define MAX3(a, b, c) fmaxf(fmaxf((a), (b)), (c))

#define MFMA16(a, b, c) __builtin_amdgcn_mfma_f32_16x16x32_bf16(a, b, c, 0, 0, 0)
#define MFMA32(a, b, c) __builtin_amdgcn_mfma_f32_32x32x16_bf16(a, b, c, 0, 0, 0)
// full-rank row swizzle (flash): rows r, r+8, ... get distinct granule perms
#define SWZ(r) ((((r) & 7) ^ (((r) >> 3) & 7)))

// ------------- fused prep: x->bf16, W->bf16, RoPE tables (one dispatch) -----
__global__ void __launch_bounds__(256) prep(const float* __restrict__ x,
                                            const float* __restrict__ Wq,
                                            const float* __restrict__ Wk,
                                            const float* __restrict__ Wv,
                                            const float* __restrict__ Wo,
                                            const int* __restrict__ pos,
                                            unsigned short* __restrict__ xbf,
                                            unsigned short* __restrict__ wqkv,
                                            unsigned short* __restrict__ wobf,
                                            float* __restrict__ ctab,
                                            float* __restrict__ stab) {
  int blk = blockIdx.x;
  if (blk < 4096) {                           // x: 8M floats, 8/thread
    int i = blk * 256 + threadIdx.x;
    f32x4 a = ((const f32x4*)x)[i * 2];
    f32x4 b = ((const f32x4*)x)[i * 2 + 1];
    s16x8 o;
#pragma unroll
    for (int j = 0; j < 4; ++j) o[j] = (short)f2bf(a[j]);
#pragma unroll
    for (int j = 0; j < 4; ++j) o[4 + j] = (short)f2bf(b[j]);
    ((s16x8*)xbf)[i] = o;
  } else if (blk < 6144) {                    // weights: 4 x 1M floats
    int wsel = (blk - 4096) >> 9;             // 512 blocks per matrix
    const float* src = wsel == 0 ? Wq : wsel == 1 ? Wk : wsel == 2 ? Wv : Wo;
    unsigned short* dst = (wsel < 3) ? (wqkv + (size_t)wsel * DMODEL * DMODEL) : wobf;
    int i = ((blk - 4096) & 511) * 256 + threadIdx.x;
    f32x4 a = ((const f32x4*)src)[i * 2];
    f32x4 b = ((const f32x4*)src)[i * 2 + 1];
    s16x8 o;
#pragma unroll
    for (int j = 0; j < 4; ++j) o[j] = (short)f2bf(a[j]);
#pragma unroll
    for (int j = 0; j < 4; ++j) o[4 + j] = (short)f2bf(b[j]);
    ((s16x8*)dst)[i] = o;
  } else {                                    // rope tables: 65536 entries
    int g = (blk - 6144) * 256 + threadIdx.x;
    int s = g >> 5, i = g & 31;
    float p = (float)pos[s];
    float ang = p * exp2f(-(float)i * 0.41524101186092029f);
    ctab[g] = cosf(ang);
    stab[g] = sinf(ang);
  }
}

// ---------------- QKV GEMM: C[8192][3072] = x * W_qkv^T, 128x128 tile -------
// Measured optimum of the 2-phase counted-vmcnt family (R18-R25 sweep:
// >=3 blocks/CU beats every per-wave-intensity or per-barrier-amortization
// variant). 3-buffer 2-deep prefetch, single barrier, 3 blocks/CU.
// V^T store quad-permutes k {0,8,4,12} per 16-group so flash PV is one b128.
__global__ void __launch_bounds__(256) gemm_qkv(const unsigned short* __restrict__ A,
                                                const unsigned short* __restrict__ B,
                                                unsigned short* __restrict__ dstQ,
                                                unsigned short* __restrict__ dstK,
                                                unsigned short* __restrict__ dstV,
                                                const float* __restrict__ ctab,
                                                const float* __restrict__ stab,
                                                float scale) {
  __shared__ unsigned short ldsA[3][128 * 32];
  __shared__ unsigned short ldsB[3][128 * 32];
  const int tid = threadIdx.x;
  const int lane = tid & 63;
  const int wave = tid >> 6;
  const int wm = wave >> 1, wn = wave & 1;

  int flat = blockIdx.y * 24 + blockIdx.x;    // 1536 blocks
  int xcd = flat & 7, idx = flat >> 3;        // idx 0..191 (per-XCD issue order)
  int g = idx >> 6;                           // n-group 0..2 (8 n-blocks each)
  int local = idx & 63;
  int lm = local >> 3, ln = local & 7;
  const int m0 = (xcd * 8 + lm) * 128;
  const int n0 = (g * 8 + ln) * 128;
  const int l15 = lane & 15, lhi = lane >> 4;

  f32x4 acc[4][4] = {};

  auto stage = [&](int buf, int kt) {
    const int kbase = kt * 32;
#pragma unroll
    for (int issue = 0; issue < 2; ++issue) {
      int c = issue * 256 + wave * 64 + lane;   // chunk id 0..511
      int row = c >> 2, kc = c & 3;
      int kcg = kc ^ ((row >> 1) & 3);          // source chunk for this slot
      gload_lds16(A + (size_t)(m0 + row) * 1024 + kbase + kcg * 8,
                  &ldsA[buf][(issue * 256 + wave * 64) * 8]);
      gload_lds16(B + (size_t)(n0 + row) * 1024 + kbase + kcg * 8,
                  &ldsB[buf][(issue * 256 + wave * 64) * 8]);
    }
  };

  stage(0, 0);
  stage(1, 1);
  for (int kt = 0; kt < 32; ++kt) {
    if (kt + 1 < 32) {
      asm volatile("s_waitcnt vmcnt(4)" ::: "memory");
    } else {
      asm volatile("s_waitcnt vmcnt(0)" ::: "memory");
    }
    __builtin_amdgcn_s_barrier();
    __builtin_amdgcn_sched_barrier(0);
    if (kt + 2 < 32) stage((kt + 2) % 3, kt + 2);

    const int buf = kt % 3;
    s16x8 af[4], bf[4];
#pragma unroll
    for (int mi = 0; mi < 4; ++mi) {
      int row = wm * 64 + mi * 16 + l15;
      int kc = lhi ^ ((row >> 1) & 3);
      af[mi] = *(const s16x8*)&ldsA[buf][row * 32 + kc * 8];
    }
#pragma unroll
    for (int ni = 0; ni < 4; ++ni) {
      int row = wn * 64 + ni * 16 + l15;
      int kc = lhi ^ ((row >> 1) & 3);
      bf[ni] = *(const s16x8*)&ldsB[buf][row * 32 + kc * 8];
    }
    __builtin_amdgcn_s_setprio(1);
#pragma unroll
    for (int mi = 0; mi < 4; ++mi)
#pragma unroll
      for (int ni = 0; ni < 4; ++ni)
        acc[mi][ni] = MFMA16(af[mi], bf[ni], acc[mi][ni]);
    __builtin_amdgcn_s_setprio(0);
  }

  // epilogue: C layout col = lane&15, row = (lane>>4)*4 + i
  const int which = n0 >> 10;                 // 0=Q 1=K 2=V (uniform per block)
  if (which < 2) {
    unsigned short* dst = (which == 0) ? dstQ : dstK;
    const float sc = (which == 0) ? scale : 1.0f;
#pragma unroll
    for (int mi = 0; mi < 4; ++mi)
#pragma unroll
      for (int ni = 0; ni < 4; ++ni)
#pragma unroll
        for (int i = 0; i < 4; ++i) {
          int r = m0 + wm * 64 + mi * 16 + lhi * 4 + i;
          int nn = (n0 & 1023) + wn * 64 + ni * 16 + l15;
          float v = acc[mi][ni][i];
          float p = __shfl_xor(v, 1);           // RoPE partner
          int s = r & (SLEN - 1);
          int d = nn & 63;
          int fi = d >> 1;
          float c = ctab[s * 32 + fi], sn = stab[s * 32 + fi];
          float o = (d & 1) ? (p * sn + v * c) : (v * c - p * sn);
          o *= sc;
          int b = r >> 11, h = nn >> 6;
          dst[((size_t)(b * NHEADS + h) * SLEN + s) * 64 + d] = f2bf(o);
        }
  } else {  // V^T [bh][d][s], quad-permuted k-order (swap bits 2<->3 of s)
#pragma unroll
    for (int mi = 0; mi < 4; ++mi)
#pragma unroll
      for (int ni = 0; ni < 4; ++ni) {
        int r0 = m0 + wm * 64 + mi * 16 + lhi * 4;
        int nn = (n0 & 1023) + wn * 64 + ni * 16 + l15;
        int b = r0 >> 11, s0 = r0 & (SLEN - 1);
        int s0p = (s0 & ~15) | ((lhi & 1) << 3) | ((lhi & 2) << 1);
        int h = nn >> 6, d = nn & 63;
        s16x4 pk;
#pragma unroll
        for (int i = 0; i < 4; ++i) pk[i] = (short)f2bf(acc[mi][ni][i]);
        *(s16x4*)&dstV[((size_t)(b * NHEADS + h) * 64 + d) * SLEN + s0p] = pk;
      }
  }
}

// ---------------- Wo GEMM: out[8192][1024] = Obf * Wo^T (fp32 out) ----------
__global__ void __launch_bounds__(256) gemm_wo(const unsigned short* __restrict__ A,
                                               const unsigned short* __restrict__ B,
                                               float* __restrict__ dst) {
  __shared__ unsigned short ldsA[3][128 * 32];
  __shared__ unsigned short ldsB[3][128 * 32];
  const int tid = threadIdx.x;
  const int lane = tid & 63;
  const int wave = tid >> 6;
  const int wm = wave >> 1, wn = wave & 1;

  int flat = blockIdx.y * 8 + blockIdx.x;     // 512 blocks
  int logical = (flat & 7) * 64 + (flat >> 3);
  const int m0 = (logical >> 3) * 128;
  const int n0 = (logical & 7) * 128;
  const int l15 = lane & 15, lhi = lane >> 4;

  f32x4 acc[4][4] = {};

  auto stage = [&](int buf, int kt) {
    const int kbase = kt * 32;
#pragma unroll
    for (int issue = 0; issue < 2; ++issue) {
      int c = issue * 256 + wave * 64 + lane;
      int row = c >> 2, kc = c & 3;
      int kcg = kc ^ ((row >> 1) & 3);
      gload_lds16(A + (size_t)(m0 + row) * 1024 + kbase + kcg * 8,
                  &ldsA[buf][(issue * 256 + wave * 64) * 8]);
      gload_lds16(B + (size_t)(n0 + row) * 1024 + kbase + kcg * 8,
                  &ldsB[buf][(issue * 256 + wave * 64) * 8]);
    }
  };

  stage(0, 0);
  stage(1, 1);
  for (int kt = 0; kt < 32; ++kt) {
    if (kt + 1 < 32) {
      asm volatile("s_waitcnt vmcnt(4)" ::: "memory");
    } else {
      asm volatile("s_waitcnt vmcnt(0)" ::: "memory");
    }
    __builtin_amdgcn_s_barrier();
    __builtin_amdgcn_sched_barrier(0);
    if (kt + 2 < 32) stage((kt + 2) % 3, kt + 2);

    const int buf = kt % 3;
    s16x8 af[4], bf[4];
#pragma unroll
    for (int mi = 0; mi < 4; ++mi) {
      int row = wm * 64 + mi * 16 + l15;
      int kc = lhi ^ ((row >> 1) & 3);
      af[mi] = *(const s16x8*)&ldsA[buf][row * 32 + kc * 8];
    }
#pragma unroll
    for (int ni = 0; ni < 4; ++ni) {
      int row = wn * 64 + ni * 16 + l15;
      int kc = lhi ^ ((row >> 1) & 3);
      bf[ni] = *(const s16x8*)&ldsB[buf][row * 32 + kc * 8];
    }
    __builtin_amdgcn_s_setprio(1);
#pragma unroll
    for (int mi = 0; mi < 4; ++mi)
#pragma unroll
      for (int ni = 0; ni < 4; ++ni)
        acc[mi][ni] = MFMA16(af[mi], bf[ni], acc[mi][ni]);
    __builtin_amdgcn_s_setprio(0);
  }

#pragma unroll
  for (int mi = 0; mi < 4; ++mi)
#pragma unroll
    for (int ni = 0; ni < 4; ++ni)
#pragma unroll
      for (int i = 0; i < 4; ++i) {
        int r = m0 + wm * 64 + mi * 16 + lhi * 4 + i;
        int n = n0 + wn * 64 + ni * 16 + l15;
        dst[(size_t)r * 1024 + n] = acc[mi][ni][i];
      }
}

// ---------------- causal flash attention, v19 (R24, passing, best) ----------
__global__ void __launch_bounds__(256, 4) flash_attn(const unsigned short* __restrict__ Q,
                                                     const unsigned short* __restrict__ K,
                                                     const unsigned short* __restrict__ Vt,
                                                     unsigned short* __restrict__ Obf) {
  __shared__ unsigned short Kbuf[2][64 * 64];   // 8 KB each
  __shared__ unsigned short Vbuf[2][64 * 64];   // rows = d, cols = permuted k

  const int tid = threadIdx.x, lane = tid & 63, w = tid >> 6;
  const int l31 = lane & 31, h = lane >> 5;     // h: which 32-lane half

  // XCD round-robin extraction + Graeco-Latin balanced (bh, t)
  int id = blockIdx.x;                          // 0..1023
  int xcd = id & 7, idx = id >> 3;              // idx 0..127 per XCD
  const int s_ = idx & 3;
  const int bhl = (idx >> 2) & 7;
  const int g_ = idx >> 5;
  const int mul2g = (g_ == 0) ? 0 : (g_ == 1) ? 2 : (g_ == 2) ? 3 : 1;
  const int t = 4 * (s_ ^ g_) + (s_ ^ mul2g);   // 0..15, balanced both ways
  const int bh = xcd * 8 + bhl;
  const int b = bh >> 4, hd = bh & 15;

  const unsigned short* Qb = Q + (size_t)bh * SLEN * 64;
  const unsigned short* Kb = K + (size_t)bh * SLEN * 64;
  const unsigned short* Vb = Vt + (size_t)bh * 64 * SLEN;

  const int qbase = t * 128;
  const int nt = 2 * t + 2;                     // k-tiles incl. diagonal
  const int q_abs = qbase + w * 32 + l31;
  const int qminw = qbase + w * 32;

  auto stageKV = [&](int buf, int k0) {
#pragma unroll
    for (int i = 0; i < 2; ++i) {
      int c = i * 256 + tid;                    // 16B chunk 0..511
      int row = c >> 3, cg = c & 7;
      int col = ((cg ^ SWZ(row)) * 8);
      gload_lds16(Kb + (size_t)(k0 + row) * 64 + col, &Kbuf[buf][c * 8]);
      gload_lds16(Vb + (size_t)row * SLEN + k0 + col, &Vbuf[buf][c * 8]);
    }
  };

  s16x8 qf[4];
#pragma unroll
  for (int dc = 0; dc < 4; ++dc)
    qf[dc] = *(const s16x8*)&Qb[(size_t)q_abs * 64 + dc * 16 + h * 8];

  f32x16 accT[2] = {};
  float m_run = -3.0e38f, l_run = 0.f;

  stageKV(0, 0);
  for (int kt = 0; kt < nt; ++kt) {
    const int cur = kt & 1;
    const int k0 = kt * 64;
    asm volatile("s_waitcnt vmcnt(0)" ::: "memory");
    __builtin_amdgcn_s_barrier();
    __builtin_amdgcn_sched_barrier(0);
    if (kt + 1 < nt) stageKV(cur ^ 1, (kt + 1) * 64);

    if (k0 <= qminw + 31) {                     // tile contributes to this wave
      f32x16 sacc[2] = {};
      __builtin_amdgcn_s_setprio(1);
#pragma unroll
      for (int kb = 0; kb < 2; ++kb) {
#pragma unroll
        for (int dc = 0; dc < 4; ++dc) {
          int r = kb * 32 + l31;
          int g = dc * 2 + h;
          s16x8 kf = *(const s16x8*)&Kbuf[cur][r * 64 + ((g ^ SWZ(r)) * 8)];
          sacc[kb] = MFMA32(kf, qf[dc], sacc[kb]);
        }
      }
      __builtin_amdgcn_s_setprio(0);

      if (k0 + 63 > qminw) {
#pragma unroll
        for (int kb = 0; kb < 2; ++kb)
#pragma unroll
          for (int r = 0; r < 16; ++r) {
            int k_abs = k0 + kb * 32 + (r & 3) + 8 * (r >> 2) + 4 * h;
            if (k_abs > q_abs) sacc[kb][r] = -3.0e38f;
          }
      }

      // 32-value max via v_max3 trees (T17)
      float q0 = MAX3(MAX3(sacc[0][0], sacc[1][0], sacc[0][4]),
                      MAX3(sacc[1][4], sacc[0][8], sacc[1][8]),
                      fmaxf(sacc[0][12], sacc[1][12]));
      float q1 = MAX3(MAX3(sacc[0][1], sacc[1][1], sacc[0][5]),
                      MAX3(sacc[1][5], sacc[0][9], sacc[1][9]),
                      fmaxf(sacc[0][13], sacc[1][13]));
      float q2 = MAX3(MAX3(sacc[0][2], sacc[1][2], sacc[0][6]),
                      MAX3(sacc[1][6], sacc[0][10], sacc[1][10]),
                      fmaxf(sacc[0][14], sacc[1][14]));
      float q3 = MAX3(MAX3(sacc[0][3], sacc[1][3], sacc[0][7]),
                      MAX3(sacc[1][7], sacc[0][11], sacc[1][11]),
                      fmaxf(sacc[0][15], sacc[1][15]));
      float mx = MAX3(fmaxf(q0, q1), q2, q3);
      mx = fmaxf(mx, __shfl_xor(mx, 32));

      // T13 defer-max: rescale only when max grows by > 8 (exp2 domain)
      if (!__all(mx - m_run <= 8.0f)) {
        float mnew = fmaxf(m_run, mx);
        float facv = EXP2R(m_run - mnew);
        m_run = mnew;
        l_run *= facv;
#pragma unroll
        for (int db = 0; db < 2; ++db)
#pragma unroll
          for (int r = 0; r < 16; ++r) accT[db][r] *= facv;
      }

      float s0 = 0.f, s1 = 0.f, s2 = 0.f, s3 = 0.f;
#pragma unroll
      for (int kb = 0; kb < 2; ++kb)
#pragma unroll
        for (int r = 0; r < 16; r += 4) {
          float e0 = EXP2R(sacc[kb][r + 0] - m_run);
          float e1 = EXP2R(sacc[kb][r + 1] - m_run);
          float e2 = EXP2R(sacc[kb][r + 2] - m_run);
          float e3 = EXP2R(sacc[kb][r + 3] - m_run);
          sacc[kb][r + 0] = e0; sacc[kb][r + 1] = e1;
          sacc[kb][r + 2] = e2; sacc[kb][r + 3] = e3;
          s0 += e0; s1 += e1; s2 += e2; s3 += e3;
        }
      float sum = (s0 + s1) + (s2 + s3);
      sum += __shfl_xor(sum, 32);
      l_run += sum;

      unsigned Hv[8][2];
#pragma unroll
      for (int kb = 0; kb < 2; ++kb)
#pragma unroll
        for (int q4 = 0; q4 < 4; ++q4) {
          Hv[kb * 4 + q4][0] = cvt_pk_bf16(sacc[kb][q4 * 4 + 0], sacc[kb][q4 * 4 + 1]);
          Hv[kb * 4 + q4][1] = cvt_pk_bf16(sacc[kb][q4 * 4 + 2], sacc[kb][q4 * 4 + 3]);
        }

      // PV: B-frag lane-local; V-frag ONE b128 (granule 2kc+h, permuted k)
      __builtin_amdgcn_s_setprio(1);
#pragma unroll
      for (int db = 0; db < 2; ++db) {
        int r = db * 32 + l31;
        const char* rowp = (const char*)&Vbuf[cur][r * 64];
#pragma unroll
        for (int kc = 0; kc < 4; ++kc) {
          u32x4 vv = *(const u32x4*)(rowp + (((2 * kc + h) ^ SWZ(r)) * 16));
          u32x4 pv;
          pv[0] = Hv[2 * kc][0]; pv[1] = Hv[2 * kc][1];
          pv[2] = Hv[2 * kc + 1][0]; pv[3] = Hv[2 * kc + 1][1];
          accT[db] = MFMA32(__builtin_bit_cast(s16x8, vv),
                            __builtin_bit_cast(s16x8, pv), accT[db]);
        }
      }
      __builtin_amdgcn_s_setprio(0);
    }
  }

  float linv = 1.f / l_run;
#pragma unroll
  for (int db = 0; db < 2; ++db)
#pragma unroll
    for (int q4 = 0; q4 < 4; ++q4) {
      u32x2 pk;
      pk[0] = cvt_pk_bf16(accT[db][q4 * 4 + 0] * linv, accT[db][q4 * 4 + 1] * linv);
      pk[1] = cvt_pk_bf16(accT[db][q4 * 4 + 2] * linv, accT[db][q4 * 4 + 3] * linv);
      int d0 = db * 32 + 8 * q4 + 4 * h;
      *(u32x2*)&Obf[((size_t)(b * SLEN + q_abs)) * DMODEL + hd * 64 + d0] = pk;
    }
}

extern "C" void kernel_launch(void* const* d_in, const int* in_sizes, int n_in,
                              void* d_out, int out_size, void* d_ws, size_t ws_size,
                              hipStream_t stream) {
  const float* x  = (const float*)d_in[0];
  const float* Wq = (const float*)d_in[1];
  const float* Wk = (const float*)d_in[2];
  const float* Wv = (const float*)d_in[3];
  const float* Wo = (const float*)d_in[4];
  const int* pos  = (const int*)d_in[5];
  float* out = (float*)d_out;

  char* ws = (char*)d_ws;
  size_t off = 0;
  auto take = [&](size_t bytes) {
    char* p = ws + off;
    off += (bytes + 255) & ~(size_t)255;
    return p;
  };
  unsigned short* xbf  = (unsigned short*)take((size_t)MTOT * DMODEL * 2);
  unsigned short* wqkv = (unsigned short*)take((size_t)3 * DMODEL * DMODEL * 2);
  unsigned short* wobf = (unsigned short*)take((size_t)DMODEL * DMODEL * 2);
  unsigned short* Qs   = (unsigned short*)take((size_t)64 * SLEN * 64 * 2);
  unsigned short* Ks   = (unsigned short*)take((size_t)64 * SLEN * 64 * 2);
  unsigned short* Vt   = (unsigned short*)take((size_t)64 * 64 * SLEN * 2);
  unsigned short* Obf  = (unsigned short*)take((size_t)MTOT * DMODEL * 2);
  float* ctab = (float*)take((size_t)SLEN * 32 * 4);
  float* stab = (float*)take((size_t)SLEN * 32 * 4);

  // one fused prep dispatch: x-cvt (4096 blk) + W-cvt (2048) + rope (256)
  prep<<<6400, 256, 0, stream>>>(x, Wq, Wk, Wv, Wo, pos,
                                 xbf, wqkv, wobf, ctab, stab);

  // fused QKV projection, 128x128 tiles (measured family optimum)
  gemm_qkv<<<dim3(24, 64), 256, 0, stream>>>(xbf, wqkv, Qs, Ks, Vt,
                                             ctab, stab, 0.18033688011112042f);

  flash_attn<<<1024, 256, 0, stream>>>(Qs, Ks, Vt, Obf);

  // final projection, fp32 output
  gemm_wo<<<dim3(8, 64), 256, 0, stream>>>(Obf, wobf, out);
}